// Round 3
// baseline (985.079 us; speedup 1.0000x reference)
//
#include <hip/hip_runtime.h>
#include <hip/hip_bf16.h>
#include <cstdint>
#include <cstddef>

using bf16 = __hip_bfloat16;

typedef __attribute__((ext_vector_type(4))) float f32x4;
typedef __attribute__((ext_vector_type(8))) short s16x8;

#define LSEQ 4096
#define DDIM 512
#define KFLT 24
#define NFFT 8192
#define FPAD 4224            // padded frequency count (4097 live)
#define MROWS 8448           // 2*FPAD interleaved re/im rows
#define FLIVE 8194           // 2*4097 live rows
#define TWO_PI_OVER_N 7.669903939428206e-4f

__device__ __forceinline__ void gld16(const bf16* g, bf16* l) {
  __builtin_amdgcn_global_load_lds((const __attribute__((address_space(1))) void*)g,
                                   (__attribute__((address_space(3))) void*)l, 16, 0, 0);
}

#define MEMFENCE asm volatile("" ::: "memory")
#define BAR() do { MEMFENCE; __builtin_amdgcn_s_barrier(); MEMFENCE; } while (0)

// Stage one 128x64 bf16 half-tile global->LDS, 2 gld16/wave, pre-swizzled source
// (slot ^= row&7) so the linear LDS dest holds the XOR-swizzled layout (G21).
__device__ __forceinline__ void stage_half(const bf16* g, int ldk, bf16* ldsbase,
                                           int wave, int lane) {
  const int r8 = lane >> 3;                    // row within 8-row chunk
  const int sc = ((lane & 7) ^ r8) * 8;        // swizzled source col (bf16 units)
  #pragma unroll
  for (int q = 0; q < 2; ++q) {
    const int c = wave * 2 + q;                // chunk 0..15 (wave-uniform)
    gld16(g + (size_t)(c * 8 + r8) * ldk + sc, ldsbase + c * 512);
  }
}

// -------- transpose + cast->bf16: out[c][r] = bf16(in[r][c]), batched over z
__global__ __launch_bounds__(256) void transpose_cast(
    const float* __restrict__ in, bf16* __restrict__ out, int R, int C) {
  __shared__ float tile[32][33];
  const size_t bo = (size_t)blockIdx.z * R * C;
  const float* inb = in + bo;
  bf16* outb = out + bo;
  int c0 = blockIdx.x * 32, r0 = blockIdx.y * 32;
  int tx = threadIdx.x & 31, ty = threadIdx.x >> 5;
  #pragma unroll
  for (int i = 0; i < 32; i += 8)
    tile[ty + i][tx] = inb[(size_t)(r0 + ty + i) * C + (c0 + tx)];
  __syncthreads();
  #pragma unroll
  for (int i = 0; i < 32; i += 8)
    outb[(size_t)(c0 + ty + i) * R + (r0 + tx)] = __float2bfloat16(tile[tx][ty + i]);
}

// -------- elementwise f32 -> bf16 cast, 8 elems/thread
__global__ __launch_bounds__(256) void cast_f32_bf16(
    const float* __restrict__ in, bf16* __restrict__ out, int n) {
  int i = (blockIdx.x * 256 + threadIdx.x) * 8;
  if (i >= n) return;
  const float4 a = *(const float4*)(in + i);
  const float4 b = *(const float4*)(in + i + 4);
  bf16 o[8] = {__float2bfloat16(a.x), __float2bfloat16(a.y),
               __float2bfloat16(a.z), __float2bfloat16(a.w),
               __float2bfloat16(b.x), __float2bfloat16(b.y),
               __float2bfloat16(b.z), __float2bfloat16(b.w)};
  *(s16x8*)(out + i) = *(const s16x8*)o;
}

// -------- forward-DFT matrix, interleaved rows: W[2f][t]=cos, W[2f+1][t]=-sin
__global__ __launch_bounds__(256) void gen_w(bf16* __restrict__ W) {
  int r = blockIdx.y;
  int t = blockIdx.x * 256 + threadIdx.x;
  float v = 0.f;
  if (r < FLIVE) {
    int f = r >> 1;
    int m = (f * t) & (NFFT - 1);
    float s, c;
    __sincosf((float)m * TWO_PI_OVER_N, &s, &c);
    v = (r & 1) ? -s : c;
  }
  W[(size_t)r * LSEQ + t] = __float2bfloat16(v);
}

// -------- inverse-DFT matrix: Cinv[l][2f]=wf/N*cos, Cinv[l][2f+1]=-wf/N*sin
__global__ __launch_bounds__(256) void gen_cinv(bf16* __restrict__ Cinv) {
  int l = blockIdx.y;
  int r = blockIdx.x * 256 + threadIdx.x;
  float v = 0.f;
  if (r < FLIVE) {
    int f = r >> 1;
    int m = (f * l) & (NFFT - 1);
    float s, c;
    __sincosf((float)m * TWO_PI_OVER_N, &s, &c);
    float wf = (f == 0 || f == NFFT / 2) ? 1.f : 2.f;
    float scale = wf * (1.f / NFFT);
    v = (r & 1) ? -scale * s : scale * c;
  }
  Cinv[(size_t)l * MROWS + r] = __float2bfloat16(v);
}

// -------- Pf[f][k] = sum_t phi[t][k] e^{-2pi i f t/N}, stored [f][k][re,im] f32
__global__ __launch_bounds__(256) void compute_pf(
    const float* __restrict__ phi, float* __restrict__ Pf) {
  int f = blockIdx.x;
  int tid = threadIdx.x;
  int lane = tid & 63, wave = tid >> 6;
  float pre[KFLT], pim[KFLT];
  #pragma unroll
  for (int k = 0; k < KFLT; ++k) { pre[k] = 0.f; pim[k] = 0.f; }
  for (int cch = 0; cch < LSEQ / 256; ++cch) {
    int t = cch * 256 + tid;
    int m = (f * t) & (NFFT - 1);
    float s, c;
    __sincosf((float)m * TWO_PI_OVER_N, &s, &c);
    const float4* pv = (const float4*)(phi + (size_t)t * KFLT);
    float4 v0 = pv[0], v1 = pv[1], v2 = pv[2], v3 = pv[3], v4 = pv[4], v5 = pv[5];
    float pr[KFLT] = {v0.x, v0.y, v0.z, v0.w, v1.x, v1.y, v1.z, v1.w,
                      v2.x, v2.y, v2.z, v2.w, v3.x, v3.y, v3.z, v3.w,
                      v4.x, v4.y, v4.z, v4.w, v5.x, v5.y, v5.z, v5.w};
    #pragma unroll
    for (int k = 0; k < KFLT; ++k) {
      pre[k] += pr[k] * c;
      pim[k] -= pr[k] * s;
    }
  }
  __shared__ float red[4][2 * KFLT];
  #pragma unroll
  for (int k = 0; k < KFLT; ++k) {
    float r = pre[k], i2 = pim[k];
    #pragma unroll
    for (int off = 32; off > 0; off >>= 1) {
      r += __shfl_down(r, off, 64);
      i2 += __shfl_down(i2, off, 64);
    }
    if (lane == 0) { red[wave][2 * k] = r; red[wave][2 * k + 1] = i2; }
  }
  __syncthreads();
  if (tid < 2 * KFLT)
    Pf[(size_t)f * (2 * KFLT) + tid] =
        red[0][tid] + red[1][tid] + red[2][tid] + red[3][tid];
}

// -------- Pw[j][f][re,im]: j<24 plus = Pf[f][k]; j>=24 minus = conj(Pf[4096-f][k])
__global__ __launch_bounds__(256) void build_pw(
    const float* __restrict__ Pf, float* __restrict__ Pw) {
  int idx = blockIdx.x * 256 + threadIdx.x;
  if (idx >= 48 * FPAD) return;
  int j = idx / FPAD, f = idx % FPAD;
  float re = 0.f, im = 0.f;
  if (f <= NFFT / 2) {
    if (j < KFLT) {
      re = Pf[(size_t)f * 48 + j * 2];
      im = Pf[(size_t)f * 48 + j * 2 + 1];
    } else {
      int k = j - KFLT, g = NFFT / 2 - f;
      re = Pf[(size_t)g * 48 + k * 2];
      im = -Pf[(size_t)g * 48 + k * 2 + 1];
    }
  }
  Pw[(size_t)idx * 2] = re;
  Pw[(size_t)idx * 2 + 1] = im;
}

// ======== phase-interleaved GEMM, C = A[M,K] @ Bt[N,K]^T  (8-phase-template port)
// BM=256, BK=64, 8 waves = full-height column strips. Double-buffered LDS,
// XOR-swizzled (T2), counted vmcnt (T3+T4), setprio around MFMA (T5), XCD swizzle (T1).
// EPI 1: BN=128, 2 phases/tile; j-stream of jcount GEMMs with complex Pw epilogue
//        into yacc, final atomicAdd f32.
// EPI 3: BN=256, 4 phases/tile; split-K over blockIdx.z, atomicAdd f32.
template <int EPI>
__global__ __launch_bounds__(512, 2) void gemm8(
    const bf16* __restrict__ A, const bf16* __restrict__ Bt,
    int N, int Kin, float* __restrict__ Cf,
    const float* __restrict__ Pw, int jcount, int nsplit) {
  constexpr int NF  = (EPI == 1) ? 1 : 2;     // n-frags per wave
  constexpr int BN  = 128 * NF;
  constexpr int NPH = (EPI == 1) ? 2 : 4;     // phases per K-tile
  constexpr int MFP = 16 / NPH;               // m-frags per phase

  __shared__ bf16 sA[2 * 256 * 64];
  __shared__ bf16 sB[2 * BN * 64];

  // bijective XCD-aware swizzle (m204)
  const int gx = gridDim.x, gy = gridDim.y;
  const int nwg = gx * gy * gridDim.z;
  const int lin = blockIdx.x + gx * (blockIdx.y + gy * blockIdx.z);
  const int q8 = nwg >> 3, r8g = nwg & 7;
  const int xcd = lin & 7, pos = lin >> 3;
  const int wid = (xcd < r8g ? xcd * (q8 + 1) : r8g * (q8 + 1) + (xcd - r8g) * q8) + pos;
  const int bx = wid % gx;
  const int tmp = wid / gx;
  const int by = tmp % gy, bz = tmp / gy;

  const int tid = threadIdx.x;
  const int lane = tid & 63, wave = tid >> 6;
  const int l15 = lane & 15, l4 = lane >> 4;
  const int mtile = by * 256, ntile = bx * BN;

  const bf16* Abase = A + (size_t)mtile * Kin;
  const bf16* Bbase = Bt + (size_t)ntile * Kin;

  int NT, kt0 = 0;
  if constexpr (EPI == 1) {
    NT = jcount * 8;                          // Kin==512: 8 K-tiles per j
  } else {
    int tot = Kin >> 6;
    kt0 = bz * tot / nsplit;
    NT = (bz + 1) * tot / nsplit - kt0;
  }

  auto ktOf = [&](int s2) { return (EPI == 1) ? (s2 & 7) : (kt0 + s2); };
  auto aPtr = [&](int s2, int h) {
    return Abase + (size_t)(h * 128) * Kin + (size_t)ktOf(s2) * 64;
  };
  auto bPtr = [&](int s2, int h) {
    const bf16* bb = Bbase;
    if constexpr (EPI == 1) bb += (size_t)(bz * jcount + (s2 >> 3)) * (DDIM * DDIM);
    return bb + (size_t)(h * 128) * Kin + (size_t)ktOf(s2) * 64;
  };

  f32x4 acc[16][NF];
  #pragma unroll
  for (int m = 0; m < 16; ++m)
    #pragma unroll
    for (int n = 0; n < NF; ++n)
      acc[m][n] = f32x4{0.f, 0.f, 0.f, 0.f};
  f32x4 yacc[(EPI == 1) ? 16 : 1];
  #pragma unroll
  for (int m = 0; m < ((EPI == 1) ? 16 : 1); ++m)
    yacc[m] = f32x4{0.f, 0.f, 0.f, 0.f};

  // ---- prologue: stage tile 0 (order B[,B1],A0,A1), counted wait leaves A1 in flight
  if constexpr (EPI == 1) {
    stage_half(bPtr(0, 0), Kin, sB, wave, lane);
    stage_half(aPtr(0, 0), Kin, sA, wave, lane);
    stage_half(aPtr(0, 1), Kin, sA + 128 * 64, wave, lane);
  } else {
    stage_half(bPtr(0, 0), Kin, sB, wave, lane);
    stage_half(bPtr(0, 1), Kin, sB + 128 * 64, wave, lane);
    stage_half(aPtr(0, 0), Kin, sA, wave, lane);
    stage_half(aPtr(0, 1), Kin, sA + 128 * 64, wave, lane);
  }
  asm volatile("s_waitcnt vmcnt(2)" ::: "memory");
  BAR();

  for (int s = 0; s < NT; ++s) {
    const int par = s & 1, nb = par ^ 1;
    bf16* bA = sA + par * (256 * 64);
    bf16* bB = sB + par * (BN * 64);
    const bool more = (s + 1 < NT);

    // B-frags for the whole tile (wave's column strip), swizzled read
    s16x8 bfr[NF][2];
    #pragma unroll
    for (int n = 0; n < NF; ++n)
      #pragma unroll
      for (int kk = 0; kk < 2; ++kk) {
        int row = wave * (16 * NF) + n * 16 + l15;
        bfr[n][kk] =
            *(const s16x8*)(bB + row * 64 + (((kk * 4 + l4) ^ (l15 & 7)) * 8));
      }

    #pragma unroll
    for (int p = 0; p < NPH; ++p) {
      // A-frags for this phase (A-half = p*MFP/8 — staggered consumption)
      s16x8 afr[MFP][2];
      #pragma unroll
      for (int i = 0; i < MFP; ++i)
        #pragma unroll
        for (int kk = 0; kk < 2; ++kk) {
          int row = (p * MFP + i) * 16 + l15;
          afr[i][kk] =
              *(const s16x8*)(bA + row * 64 + (((kk * 4 + l4) ^ (l15 & 7)) * 8));
        }
      // stage next tile's half-tile(s): order B[,B1],A0,A1 across phases
      if (more) {
        if constexpr (EPI == 1) {
          if (p == 0) {
            stage_half(bPtr(s + 1, 0), Kin, sB + nb * (BN * 64), wave, lane);
            stage_half(aPtr(s + 1, 0), Kin, sA + nb * (256 * 64), wave, lane);
          } else {
            stage_half(aPtr(s + 1, 1), Kin, sA + nb * (256 * 64) + 128 * 64, wave, lane);
          }
        } else {
          if (p == 0) stage_half(bPtr(s + 1, 0), Kin, sB + nb * (BN * 64), wave, lane);
          if (p == 1) stage_half(bPtr(s + 1, 1), Kin, sB + nb * (BN * 64) + 128 * 64, wave, lane);
          if (p == 2) stage_half(aPtr(s + 1, 0), Kin, sA + nb * (256 * 64), wave, lane);
          if (p == 3) stage_half(aPtr(s + 1, 1), Kin, sA + nb * (256 * 64) + 128 * 64, wave, lane);
        }
      }
      BAR();
      __builtin_amdgcn_s_setprio(1);
      #pragma unroll
      for (int i = 0; i < MFP; ++i)
        #pragma unroll
        for (int n = 0; n < NF; ++n)
          #pragma unroll
          for (int kk = 0; kk < 2; ++kk)
            acc[p * MFP + i][n] = __builtin_amdgcn_mfma_f32_16x16x32_bf16(
                afr[i][kk], bfr[n][kk], acc[p * MFP + i][n], 0, 0, 0);
      __builtin_amdgcn_s_setprio(0);
      // counted vmcnt: mid-tile forces prev A1; tile-end forces next B,A0 (leaves A1)
      if (p == NPH / 2 - 1) {
        if (more) { asm volatile("s_waitcnt vmcnt(4)" ::: "memory"); }
        else      { asm volatile("s_waitcnt vmcnt(0)" ::: "memory"); }
      }
      if (p == NPH - 1 && more) {
        asm volatile("s_waitcnt vmcnt(2)" ::: "memory");
      }
      BAR();
    }

    if constexpr (EPI == 1) {
      if ((s & 7) == 7) {   // end of one j-GEMM: complex-weighted accumulate
        const int j = bz * jcount + (s >> 3);
        #pragma unroll
        for (int mf = 0; mf < 16; ++mf) {
          const int rbase = mtile + mf * 16 + l4 * 4;   // even
          #pragma unroll
          for (int pp = 0; pp < 2; ++pp) {
            const int f = (rbase >> 1) + pp;
            float2 w = *(const float2*)(Pw + ((size_t)j * FPAD + f) * 2);
            float vre = acc[mf][0][2 * pp], vim = acc[mf][0][2 * pp + 1];
            yacc[mf][2 * pp]     += w.x * vre - w.y * vim;
            yacc[mf][2 * pp + 1] += w.x * vim + w.y * vre;
          }
          acc[mf][0] = f32x4{0.f, 0.f, 0.f, 0.f};
        }
      }
    }
  }

  if constexpr (EPI == 1) {
    #pragma unroll
    for (int mf = 0; mf < 16; ++mf)
      #pragma unroll
      for (int e = 0; e < 4; ++e) {
        int row = mtile + mf * 16 + l4 * 4 + e;
        int col = ntile + wave * 16 + l15;
        atomicAdd(&Cf[(size_t)row * N + col], yacc[mf][e]);
      }
  } else {
    #pragma unroll
    for (int mf = 0; mf < 16; ++mf)
      #pragma unroll
      for (int n = 0; n < NF; ++n)
        #pragma unroll
        for (int e = 0; e < 4; ++e) {
          int row = mtile + mf * 16 + l4 * 4 + e;
          int col = ntile + wave * 16 * NF + n * 16 + l15;
          atomicAdd(&Cf[(size_t)row * N + col], acc[mf][n][e]);
        }
  }
}

// ---------------- workspace layout (bytes) ----------------
#define WS_W     0ULL                    // 8448*4096 bf16 = 69,206,016  (Wdft, later Cinv)
#define WS_AUF   69206016ULL             // 8448*512  bf16 =  8,650,752
#define WS_UT    77856768ULL             // 512*4096  bf16 =  4,194,304
#define WS_MT    82051072ULL             // 48*512*512 bf16 = 25,165,824
#define WS_PF    107216896ULL            // 4097*48 f32    =    786,624
#define WS_PW    108003520ULL            // 48*4224*2 f32  =  1,622,016
#define WS_YSUM  109625536ULL            // 8448*512 f32   = 17,301,504
#define WS_YBT   126927040ULL            // 512*8448 bf16  =  8,650,752
#define WS_TOTAL 135577792ULL

extern "C" void kernel_launch(void* const* d_in, const int* in_sizes, int n_in,
                              void* d_out, int out_size, void* d_ws, size_t ws_size,
                              hipStream_t stream) {
  const float* u   = (const float*)d_in[0];   // [4096, 512]
  const float* phi = (const float*)d_in[1];   // [4096, 24]
  const float* Mp  = (const float*)d_in[2];   // [24, 512, 512]
  const float* Mm  = (const float*)d_in[3];   // [24, 512, 512]
  float* y = (float*)d_out;                   // [4096, 512]

  if (ws_size < WS_TOTAL) return;             // loud failure: output stays zero

  char* ws = (char*)d_ws;
  bf16*  W    = (bf16*)(ws + WS_W);
  bf16*  Auf  = (bf16*)(ws + WS_AUF);
  bf16*  uT   = (bf16*)(ws + WS_UT);
  bf16*  Mt   = (bf16*)(ws + WS_MT);
  float* Pf   = (float*)(ws + WS_PF);
  float* Pw   = (float*)(ws + WS_PW);
  float* Ysum = (float*)(ws + WS_YSUM);
  bf16*  Ybt  = (bf16*)(ws + WS_YBT);

  // prologue: transposed bf16 operands + spectral weight tables
  transpose_cast<<<dim3(16, 128, 1), 256, 0, stream>>>(u, uT, LSEQ, DDIM);
  transpose_cast<<<dim3(16, 16, 24), 256, 0, stream>>>(Mp, Mt, DDIM, DDIM);
  transpose_cast<<<dim3(16, 16, 24), 256, 0, stream>>>(Mm, Mt + (size_t)24 * DDIM * DDIM,
                                                       DDIM, DDIM);
  gen_w<<<dim3(16, MROWS), 256, 0, stream>>>(W);
  compute_pf<<<dim3(4097), 256, 0, stream>>>(phi, Pf);
  build_pw<<<dim3((48 * FPAD + 255) / 256), 256, 0, stream>>>(Pf, Pw);

  // G1: uf = Wdft @ u  — split-K x3 atomic into f32 Ysum, then cast to bf16 Auf
  hipMemsetAsync(Ysum, 0, (size_t)MROWS * DDIM * sizeof(float), stream);
  gemm8<3><<<dim3(2, 33, 3), 512, 0, stream>>>(W, uT, DDIM, LSEQ, Ysum, nullptr, 1, 3);
  cast_f32_bf16<<<dim3(MROWS * DDIM / (256 * 8)), 256, 0, stream>>>(
      Ysum, Auf, MROWS * DDIM);

  // G2: Ysum = sum_j Pw[j] .* (uf @ M_j)   (48 j = 4 z-groups x 12)
  hipMemsetAsync(Ysum, 0, (size_t)MROWS * DDIM * sizeof(float), stream);
  gemm8<1><<<dim3(4, 33, 4), 512, 0, stream>>>(Auf, Mt, DDIM, DDIM, Ysum, Pw, 12, 1);

  // G3: y = Cinv @ Ysum  — split-K x8 atomic into y (Cinv overwrites Wdft buffer)
  gen_cinv<<<dim3(33, LSEQ), 256, 0, stream>>>(W);
  transpose_cast<<<dim3(16, 264, 1), 256, 0, stream>>>(Ysum, Ybt, MROWS, DDIM);
  hipMemsetAsync(y, 0, (size_t)LSEQ * DDIM * sizeof(float), stream);
  gemm8<3><<<dim3(2, 16, 8), 512, 0, stream>>>(W, Ybt, DDIM, MROWS, y, nullptr, 1, 8);
}

// Round 4
// 639.148 us; speedup vs baseline: 1.5412x; 1.5412x over previous
//
#include <hip/hip_runtime.h>
#include <hip/hip_bf16.h>
#include <cstdint>
#include <cstddef>

using bf16 = __hip_bfloat16;

typedef __attribute__((ext_vector_type(4))) float f32x4;
typedef __attribute__((ext_vector_type(8))) short s16x8;

#define LSEQ 4096
#define DDIM 512
#define KFLT 24
#define NFFT 8192
#define FPAD 4224            // padded frequency count (4097 live)
#define MROWS 8448           // 2*FPAD interleaved re/im rows
#define FLIVE 8194           // 2*4097 live rows

__device__ __forceinline__ void gld16(const bf16* g, bf16* l) {
  __builtin_amdgcn_global_load_lds((const __attribute__((address_space(1))) void*)g,
                                   (__attribute__((address_space(3))) void*)l, 16, 0, 0);
}

#define MEMFENCE asm volatile("" ::: "memory")
#define BAR() do { MEMFENCE; __builtin_amdgcn_s_barrier(); MEMFENCE; } while (0)

__device__ __forceinline__ float fsin_rev(float rev) {
  float s; asm("v_sin_f32 %0, %1" : "=v"(s) : "v"(rev)); return s;
}
__device__ __forceinline__ float fcos_rev(float rev) {
  float c; asm("v_cos_f32 %0, %1" : "=v"(c) : "v"(rev)); return c;
}

// Stage one 128x64 bf16 half-tile global->LDS, 2 gld16/wave, pre-swizzled source
// (slot ^= row&7) so the linear LDS dest holds the XOR-swizzled layout (G21).
__device__ __forceinline__ void stage_half(const bf16* g, int ldk, bf16* ldsbase,
                                           int wave, int lane) {
  const int r8 = lane >> 3;
  const int sc = ((lane & 7) ^ r8) * 8;
  #pragma unroll
  for (int q = 0; q < 2; ++q) {
    const int c = wave * 2 + q;
    gld16(g + (size_t)(c * 8 + r8) * ldk + sc, ldsbase + c * 512);
  }
}

// swizzled LDS fragment read: row includes l15; 16B at slot (kk*4+l4)^(row&7)
__device__ __forceinline__ s16x8 ldfrag(const bf16* buf, int row, int kk, int l4) {
  return *(const s16x8*)(buf + row * 64 + (((kk * 4 + l4) ^ (row & 7)) * 8));
}

// -------- transpose + cast->bf16: out[c][r] = bf16(in[r][c]), batched over z
__global__ __launch_bounds__(256) void transpose_cast(
    const float* __restrict__ in, bf16* __restrict__ out, int R, int C) {
  __shared__ float tile[32][33];
  const size_t bo = (size_t)blockIdx.z * R * C;
  const float* inb = in + bo;
  bf16* outb = out + bo;
  int c0 = blockIdx.x * 32, r0 = blockIdx.y * 32;
  int tx = threadIdx.x & 31, ty = threadIdx.x >> 5;
  #pragma unroll
  for (int i = 0; i < 32; i += 8)
    tile[ty + i][tx] = inb[(size_t)(r0 + ty + i) * C + (c0 + tx)];
  __syncthreads();
  #pragma unroll
  for (int i = 0; i < 32; i += 8)
    outb[(size_t)(c0 + ty + i) * R + (r0 + tx)] = __float2bfloat16(tile[tx][ty + i]);
}

// -------- elementwise f32 -> bf16 cast, 8 elems/thread
__global__ __launch_bounds__(256) void cast_f32_bf16(
    const float* __restrict__ in, bf16* __restrict__ out, int n) {
  int i = (blockIdx.x * 256 + threadIdx.x) * 8;
  if (i >= n) return;
  const float4 a = *(const float4*)(in + i);
  const float4 b = *(const float4*)(in + i + 4);
  bf16 o[8] = {__float2bfloat16(a.x), __float2bfloat16(a.y),
               __float2bfloat16(a.z), __float2bfloat16(a.w),
               __float2bfloat16(b.x), __float2bfloat16(b.y),
               __float2bfloat16(b.z), __float2bfloat16(b.w)};
  *(s16x8*)(out + i) = *(const s16x8*)o;
}

// -------- forward-DFT matrix, interleaved rows: W[2f][t]=cos, W[2f+1][t]=-sin
// 8 elems/thread, 1 TRANS op per element (revolutions = exact m/8192)
__global__ __launch_bounds__(256) void gen_w(bf16* __restrict__ W) {
  int r = blockIdx.y;
  int t0 = (blockIdx.x * 256 + threadIdx.x) * 8;
  bf16 o[8];
  if (r < FLIVE) {
    int f = r >> 1;
    bool odd = r & 1;
    #pragma unroll
    for (int i = 0; i < 8; ++i) {
      int m = (f * (t0 + i)) & (NFFT - 1);
      float rev = (float)m * (1.f / NFFT);
      float v = odd ? -fsin_rev(rev) : fcos_rev(rev);
      o[i] = __float2bfloat16(v);
    }
  } else {
    #pragma unroll
    for (int i = 0; i < 8; ++i) o[i] = __float2bfloat16(0.f);
  }
  *(s16x8*)(W + (size_t)r * LSEQ + t0) = *(const s16x8*)o;
}

// -------- inverse-DFT matrix: Cinv[l][2f]=wf/N*cos, Cinv[l][2f+1]=-wf/N*sin
__global__ __launch_bounds__(256) void gen_cinv(bf16* __restrict__ Cinv) {
  int l = blockIdx.y;
  int r0 = (blockIdx.x * 256 + threadIdx.x) * 8;
  if (r0 >= MROWS) return;
  bf16 o[8];
  #pragma unroll
  for (int p = 0; p < 4; ++p) {
    int rr = r0 + 2 * p;
    float v0 = 0.f, v1 = 0.f;
    if (rr < FLIVE) {
      int f = rr >> 1;
      int m = (f * l) & (NFFT - 1);
      float rev = (float)m * (1.f / NFFT);
      float wf = (f == 0 || f == NFFT / 2) ? 1.f : 2.f;
      float sc = wf * (1.f / NFFT);
      v0 = sc * fcos_rev(rev);
      v1 = -sc * fsin_rev(rev);
    }
    o[2 * p] = __float2bfloat16(v0);
    o[2 * p + 1] = __float2bfloat16(v1);
  }
  *(s16x8*)(Cinv + (size_t)l * MROWS + r0) = *(const s16x8*)o;
}

// -------- Pf[f][k] = sum_t phi[t][k] e^{-2pi i f t/N}, stored [f][k][re,im] f32
__global__ __launch_bounds__(256) void compute_pf(
    const float* __restrict__ phi, float* __restrict__ Pf) {
  int f = blockIdx.x;
  int tid = threadIdx.x;
  int lane = tid & 63, wave = tid >> 6;
  float pre[KFLT], pim[KFLT];
  #pragma unroll
  for (int k = 0; k < KFLT; ++k) { pre[k] = 0.f; pim[k] = 0.f; }
  for (int cch = 0; cch < LSEQ / 256; ++cch) {
    int t = cch * 256 + tid;
    int m = (f * t) & (NFFT - 1);
    float rev = (float)m * (1.f / NFFT);
    float s = fsin_rev(rev), c = fcos_rev(rev);
    const float4* pv = (const float4*)(phi + (size_t)t * KFLT);
    float4 v0 = pv[0], v1 = pv[1], v2 = pv[2], v3 = pv[3], v4 = pv[4], v5 = pv[5];
    float pr[KFLT] = {v0.x, v0.y, v0.z, v0.w, v1.x, v1.y, v1.z, v1.w,
                      v2.x, v2.y, v2.z, v2.w, v3.x, v3.y, v3.z, v3.w,
                      v4.x, v4.y, v4.z, v4.w, v5.x, v5.y, v5.z, v5.w};
    #pragma unroll
    for (int k = 0; k < KFLT; ++k) {
      pre[k] += pr[k] * c;
      pim[k] -= pr[k] * s;
    }
  }
  __shared__ float red[4][2 * KFLT];
  #pragma unroll
  for (int k = 0; k < KFLT; ++k) {
    float r = pre[k], i2 = pim[k];
    #pragma unroll
    for (int off = 32; off > 0; off >>= 1) {
      r += __shfl_down(r, off, 64);
      i2 += __shfl_down(i2, off, 64);
    }
    if (lane == 0) { red[wave][2 * k] = r; red[wave][2 * k + 1] = i2; }
  }
  __syncthreads();
  if (tid < 2 * KFLT)
    Pf[(size_t)f * (2 * KFLT) + tid] =
        red[0][tid] + red[1][tid] + red[2][tid] + red[3][tid];
}

// -------- Pw[j][f][re,im]: j<24 plus = Pf[f][k]; j>=24 minus = conj(Pf[4096-f][k])
__global__ __launch_bounds__(256) void build_pw(
    const float* __restrict__ Pf, float* __restrict__ Pw) {
  int idx = blockIdx.x * 256 + threadIdx.x;
  if (idx >= 48 * FPAD) return;
  int j = idx / FPAD, f = idx % FPAD;
  float re = 0.f, im = 0.f;
  if (f <= NFFT / 2) {
    if (j < KFLT) {
      re = Pf[(size_t)f * 48 + j * 2];
      im = Pf[(size_t)f * 48 + j * 2 + 1];
    } else {
      int k = j - KFLT, g = NFFT / 2 - f;
      re = Pf[(size_t)g * 48 + k * 2];
      im = -Pf[(size_t)g * 48 + k * 2 + 1];
    }
  }
  Pw[(size_t)idx * 2] = re;
  Pw[(size_t)idx * 2 + 1] = im;
}

// ======== persistent phase-interleaved GEMM, C(+)= A[M,K] @ Bt[N,K]^T
// Grid = exactly 256 blocks; each owns a balanced linear range of
// (xy-tile, K-tile) units; flush (acc or weighted yacc) at xy crossings.
// 8 waves in 2D tiles; BK=64; double-buffered XOR-swizzled LDS; 2 super-phases
// per K-tile with counted vmcnt (mid: drain prev A1; end: leave next A1 in flight).
// EPI 1 (G2): BM=256,BN=128, waves 4x2 (wave 64x64), j-stream K (Kin=512 per j),
//             complex Pw weighting acc->yacc at j boundaries, atomic f32 out.
// EPI 3 (G1/G3): BM=256,BN=256, waves 2x4 (wave 128x64), plain split-K atomic out.
template <int EPI>
__global__ __launch_bounds__(512, 2) void gemmP(
    const bf16* __restrict__ A, const bf16* __restrict__ Bt,
    int ldk, int gx, int ktpxy, int total,
    float* __restrict__ Cf, const float* __restrict__ Pw) {
  constexpr int BN  = (EPI == 1) ? 128 : 256;
  constexpr int WR  = (EPI == 1) ? 4 : 2;      // wave rows
  constexpr int WC  = 8 / WR;                   // wave cols
  constexpr int RB  = 128 / WR;                 // per-wave row base step (staggered)
  constexpr int MA  = (EPI == 1) ? 4 : 8;       // m-frags per wave
  constexpr int MA2 = MA / 2;
  constexpr int NB  = 4;                        // n-frags per wave

  __shared__ bf16 sA[2 * 256 * 64];
  __shared__ bf16 sB[2 * BN * 64];

  // XCD grouping: consecutive work ranges on the same XCD
  const int lin = blockIdx.x;
  const int wid = (lin & 7) * 32 + (lin >> 3);

  const int tid = threadIdx.x;
  const int lane = tid & 63, wave = tid >> 6;
  const int l15 = lane & 15, l4 = lane >> 4;
  const int wr = wave / WC, wc = wave % WC;

  int g0 = (int)((long long)wid * total / 256);
  int g1 = (int)((long long)(wid + 1) * total / 256);
  if (g0 >= g1) return;

  int xy = g0 / ktpxy, kt = g0 - xy * ktpxy;
  int bx = xy % gx, by = xy / gx;

  auto stageA = [&](int by_, int kt_, int h, int nb_) {
    const size_t off = (size_t)((EPI == 1) ? (kt_ & 7) : kt_) * 64;
    stage_half(A + ((size_t)by_ * 256 + h * 128) * ldk + off, ldk,
               sA + nb_ * (256 * 64) + h * (128 * 64), wave, lane);
  };
  auto stageB = [&](int bx_, int kt_, int h, int nb_) {
    const size_t off = (size_t)((EPI == 1) ? (kt_ & 7) : kt_) * 64;
    const bf16* bb = Bt + ((size_t)bx_ * BN + h * 128) * ldk + off;
    if constexpr (EPI == 1) bb += (size_t)(kt_ >> 3) * (DDIM * DDIM);
    stage_half(bb, ldk, sB + nb_ * (BN * 64) + h * (128 * 64), wave, lane);
  };

  f32x4 acc[MA][NB];
  #pragma unroll
  for (int m = 0; m < MA; ++m)
    #pragma unroll
    for (int n = 0; n < NB; ++n) acc[m][n] = f32x4{0.f, 0.f, 0.f, 0.f};
  f32x4 yacc[(EPI == 1) ? MA : 1][(EPI == 1) ? NB : 1];
  #pragma unroll
  for (int m = 0; m < ((EPI == 1) ? MA : 1); ++m)
    #pragma unroll
    for (int n = 0; n < ((EPI == 1) ? NB : 1); ++n)
      yacc[m][n] = f32x4{0.f, 0.f, 0.f, 0.f};

  // prologue: stage unit g0 (B[,B1], A0, A1); leave A1 in flight
  stageB(bx, kt, 0, 0);
  if constexpr (EPI != 1) stageB(bx, kt, 1, 0);
  stageA(by, kt, 0, 0);
  stageA(by, kt, 1, 0);
  asm volatile("s_waitcnt vmcnt(2)" ::: "memory");
  BAR();

  for (int g = g0; g < g1; ++g) {
    const int par = (g - g0) & 1, nb = par ^ 1;
    const bf16* bA = sA + par * (256 * 64);
    const bf16* bB = sB + par * (BN * 64);
    const bool more = (g + 1 < g1);
    int nkt = kt + 1, nbx = bx, nby = by;
    if (nkt == ktpxy) { nkt = 0; if (++nbx == gx) { nbx = 0; ++nby; } }

    // ---- super-phase A (A-half0 rows)
    s16x8 bfr[NB][2], afr[MA2][2];
    #pragma unroll
    for (int n = 0; n < NB; ++n)
      #pragma unroll
      for (int kk = 0; kk < 2; ++kk)
        bfr[n][kk] = ldfrag(bB, wc * 64 + n * 16 + l15, kk, l4);
    #pragma unroll
    for (int i = 0; i < MA2; ++i)
      #pragma unroll
      for (int kk = 0; kk < 2; ++kk)
        afr[i][kk] = ldfrag(bA, wr * RB + i * 16 + l15, kk, l4);
    if (more) {
      stageB(nbx, nkt, 0, nb);
      if constexpr (EPI != 1) stageB(nbx, nkt, 1, nb);
      stageA(nby, nkt, 0, nb);
    }
    __builtin_amdgcn_s_setprio(1);
    #pragma unroll
    for (int i = 0; i < MA2; ++i)
      #pragma unroll
      for (int n = 0; n < NB; ++n)
        #pragma unroll
        for (int kk = 0; kk < 2; ++kk)
          acc[i][n] = __builtin_amdgcn_mfma_f32_16x16x32_bf16(
              afr[i][kk], bfr[n][kk], acc[i][n], 0, 0, 0);
    __builtin_amdgcn_s_setprio(0);
    if (more) {
      if constexpr (EPI == 1) { asm volatile("s_waitcnt vmcnt(4)" ::: "memory"); }
      else                    { asm volatile("s_waitcnt vmcnt(6)" ::: "memory"); }
    } else {
      asm volatile("s_waitcnt vmcnt(0)" ::: "memory");
    }
    BAR();

    // ---- super-phase B (A-half1 rows, +128)
    #pragma unroll
    for (int i = 0; i < MA2; ++i)
      #pragma unroll
      for (int kk = 0; kk < 2; ++kk)
        afr[i][kk] = ldfrag(bA, wr * RB + i * 16 + 128 + l15, kk, l4);
    if (more) stageA(nby, nkt, 1, nb);
    __builtin_amdgcn_s_setprio(1);
    #pragma unroll
    for (int i = 0; i < MA2; ++i)
      #pragma unroll
      for (int n = 0; n < NB; ++n)
        #pragma unroll
        for (int kk = 0; kk < 2; ++kk)
          acc[MA2 + i][n] = __builtin_amdgcn_mfma_f32_16x16x32_bf16(
              afr[i][kk], bfr[n][kk], acc[MA2 + i][n], 0, 0, 0);
    __builtin_amdgcn_s_setprio(0);
    if (more) { asm volatile("s_waitcnt vmcnt(2)" ::: "memory"); }
    BAR();

    // ---- flush logic
    const bool last = !more;
    const bool cross = more && (nkt == 0);
    if constexpr (EPI == 1) {
      if (((kt & 7) == 7) || last || cross) {
        const int j = kt >> 3;
        #pragma unroll
        for (int h = 0; h < 2; ++h)
          #pragma unroll
          for (int i = 0; i < MA2; ++i) {
            const int rbase = by * 256 + wr * RB + i * 16 + h * 128 + l4 * 4;
            #pragma unroll
            for (int pp = 0; pp < 2; ++pp) {
              const int f = (rbase >> 1) + pp;
              const float2 w = *(const float2*)(Pw + ((size_t)j * FPAD + f) * 2);
              #pragma unroll
              for (int n = 0; n < NB; ++n) {
                float re = acc[h * MA2 + i][n][2 * pp];
                float im = acc[h * MA2 + i][n][2 * pp + 1];
                yacc[h * MA2 + i][n][2 * pp]     += w.x * re - w.y * im;
                yacc[h * MA2 + i][n][2 * pp + 1] += w.x * im + w.y * re;
              }
            }
            #pragma unroll
            for (int n = 0; n < NB; ++n)
              acc[h * MA2 + i][n] = f32x4{0.f, 0.f, 0.f, 0.f};
          }
      }
      if (last || cross) {
        #pragma unroll
        for (int h = 0; h < 2; ++h)
          #pragma unroll
          for (int i = 0; i < MA2; ++i)
            #pragma unroll
            for (int n = 0; n < NB; ++n) {
              #pragma unroll
              for (int e = 0; e < 4; ++e) {
                int row = by * 256 + wr * RB + i * 16 + h * 128 + l4 * 4 + e;
                int col = bx * BN + wc * 64 + n * 16 + l15;
                atomicAdd(&Cf[(size_t)row * DDIM + col], yacc[h * MA2 + i][n][e]);
              }
              yacc[h * MA2 + i][n] = f32x4{0.f, 0.f, 0.f, 0.f};
            }
      }
    } else {
      if (last || cross) {
        #pragma unroll
        for (int h = 0; h < 2; ++h)
          #pragma unroll
          for (int i = 0; i < MA2; ++i)
            #pragma unroll
            for (int n = 0; n < NB; ++n) {
              #pragma unroll
              for (int e = 0; e < 4; ++e) {
                int row = by * 256 + wr * RB + i * 16 + h * 128 + l4 * 4 + e;
                int col = bx * BN + wc * 64 + n * 16 + l15;
                atomicAdd(&Cf[(size_t)row * DDIM + col], acc[h * MA2 + i][n][e]);
              }
              acc[h * MA2 + i][n] = f32x4{0.f, 0.f, 0.f, 0.f};
            }
      }
    }
    bx = nbx; by = nby; kt = nkt;
  }
}

// ---------------- workspace layout (bytes) ----------------
#define WS_W     0ULL                    // 8448*4096 bf16 = 69,206,016  (Wdft, later Cinv)
#define WS_AUF   69206016ULL             // 8448*512  bf16 =  8,650,752
#define WS_UT    77856768ULL             // 512*4096  bf16 =  4,194,304
#define WS_MT    82051072ULL             // 48*512*512 bf16 = 25,165,824
#define WS_PF    107216896ULL            // 4097*48 f32    =    786,624
#define WS_PW    108003520ULL            // 48*4224*2 f32  =  1,622,016
#define WS_YSUM  109625536ULL            // 8448*512 f32   = 17,301,504
#define WS_YBT   126927040ULL            // 512*8448 bf16  =  8,650,752
#define WS_TOTAL 135577792ULL

extern "C" void kernel_launch(void* const* d_in, const int* in_sizes, int n_in,
                              void* d_out, int out_size, void* d_ws, size_t ws_size,
                              hipStream_t stream) {
  const float* u   = (const float*)d_in[0];   // [4096, 512]
  const float* phi = (const float*)d_in[1];   // [4096, 24]
  const float* Mp  = (const float*)d_in[2];   // [24, 512, 512]
  const float* Mm  = (const float*)d_in[3];   // [24, 512, 512]
  float* y = (float*)d_out;                   // [4096, 512]

  if (ws_size < WS_TOTAL) return;             // loud failure: output stays zero

  char* ws = (char*)d_ws;
  bf16*  W    = (bf16*)(ws + WS_W);
  bf16*  Auf  = (bf16*)(ws + WS_AUF);
  bf16*  uT   = (bf16*)(ws + WS_UT);
  bf16*  Mt   = (bf16*)(ws + WS_MT);
  float* Pf   = (float*)(ws + WS_PF);
  float* Pw   = (float*)(ws + WS_PW);
  float* Ysum = (float*)(ws + WS_YSUM);
  bf16*  Ybt  = (bf16*)(ws + WS_YBT);

  // prologue: transposed bf16 operands + spectral weight tables
  transpose_cast<<<dim3(16, 128, 1), 256, 0, stream>>>(u, uT, LSEQ, DDIM);
  transpose_cast<<<dim3(16, 16, 24), 256, 0, stream>>>(Mp, Mt, DDIM, DDIM);
  transpose_cast<<<dim3(16, 16, 24), 256, 0, stream>>>(Mm, Mt + (size_t)24 * DDIM * DDIM,
                                                       DDIM, DDIM);
  gen_w<<<dim3(2, MROWS), 256, 0, stream>>>(W);
  compute_pf<<<dim3(4097), 256, 0, stream>>>(phi, Pf);
  build_pw<<<dim3((48 * FPAD + 255) / 256), 256, 0, stream>>>(Pf, Pw);

  // G1: uf = Wdft @ u  (M=8448, N=512, K=4096) -> f32 Ysum, then cast to bf16 Auf
  hipMemsetAsync(Ysum, 0, (size_t)MROWS * DDIM * sizeof(float), stream);
  gemmP<3><<<256, 512, 0, stream>>>(W, uT, LSEQ, 2, 64, 66 * 64, Ysum, nullptr);
  cast_f32_bf16<<<dim3(MROWS * DDIM / (256 * 8)), 256, 0, stream>>>(
      Ysum, Auf, MROWS * DDIM);

  // G2: Ysum = sum_j Pw[j] .* (uf @ M_j)  (48 j-GEMMs streamed in K)
  hipMemsetAsync(Ysum, 0, (size_t)MROWS * DDIM * sizeof(float), stream);
  gemmP<1><<<256, 512, 0, stream>>>(Auf, Mt, DDIM, 4, 384, 132 * 384, Ysum, Pw);

  // G3: y = Cinv @ Ysum  (M=4096, N=512, K=8448; Cinv overwrites Wdft buffer)
  gen_cinv<<<dim3(5, LSEQ), 256, 0, stream>>>(W);
  transpose_cast<<<dim3(16, 264, 1), 256, 0, stream>>>(Ysum, Ybt, MROWS, DDIM);
  hipMemsetAsync(y, 0, (size_t)LSEQ * DDIM * sizeof(float), stream);
  gemmP<3><<<256, 512, 0, stream>>>(W, Ybt, MROWS, 2, 132, 32 * 132, y, nullptr);
}

// Round 5
// 583.044 us; speedup vs baseline: 1.6895x; 1.0962x over previous
//
#include <hip/hip_runtime.h>
#include <hip/hip_bf16.h>
#include <cstdint>
#include <cstddef>

using bf16 = __hip_bfloat16;

typedef __attribute__((ext_vector_type(4))) float f32x4;
typedef __attribute__((ext_vector_type(8))) short s16x8;

#define LSEQ 4096
#define DDIM 512
#define KFLT 24
#define NFFT 8192
#define FPAD 4224            // padded frequency count (4097 live)
#define MROWS 8448           // 2*FPAD interleaved re/im rows
#define FLIVE 8194           // 2*4097 live rows

__device__ __forceinline__ void gld16(const bf16* g, bf16* l) {
  __builtin_amdgcn_global_load_lds((const __attribute__((address_space(1))) void*)g,
                                   (__attribute__((address_space(3))) void*)l, 16, 0, 0);
}

#define MEMFENCE asm volatile("" ::: "memory")
#define BAR() do { MEMFENCE; __builtin_amdgcn_s_barrier(); MEMFENCE; } while (0)

__device__ __forceinline__ float fsin_rev(float rev) {
  float s; asm("v_sin_f32 %0, %1" : "=v"(s) : "v"(rev)); return s;
}
__device__ __forceinline__ float fcos_rev(float rev) {
  float c; asm("v_cos_f32 %0, %1" : "=v"(c) : "v"(rev)); return c;
}

// Stage one 128x64 bf16 half-tile global->LDS, 2 gld16/wave, pre-swizzled source
// (slot ^= row&7) so the linear LDS dest holds the XOR-swizzled layout (G21).
__device__ __forceinline__ void stage_half(const bf16* g, int ldk, bf16* ldsbase,
                                           int wave, int lane) {
  const int r8 = lane >> 3;
  const int sc = ((lane & 7) ^ r8) * 8;
  #pragma unroll
  for (int q = 0; q < 2; ++q) {
    const int c = wave * 2 + q;
    gld16(g + (size_t)(c * 8 + r8) * ldk + sc, ldsbase + c * 512);
  }
}

// swizzled LDS fragment read: 16B at slot (kk*4+l4)^(row&7)
__device__ __forceinline__ s16x8 ldfrag(const bf16* buf, int row, int kk, int l4) {
  return *(const s16x8*)(buf + row * 64 + (((kk * 4 + l4) ^ (row & 7)) * 8));
}

// -------- transpose + cast->bf16: out[c][r] = bf16(in[r][c]), batched over z
__global__ __launch_bounds__(256) void transpose_cast(
    const float* __restrict__ in, bf16* __restrict__ out, int R, int C) {
  __shared__ float tile[32][33];
  const size_t bo = (size_t)blockIdx.z * R * C;
  const float* inb = in + bo;
  bf16* outb = out + bo;
  int c0 = blockIdx.x * 32, r0 = blockIdx.y * 32;
  int tx = threadIdx.x & 31, ty = threadIdx.x >> 5;
  #pragma unroll
  for (int i = 0; i < 32; i += 8)
    tile[ty + i][tx] = inb[(size_t)(r0 + ty + i) * C + (c0 + tx)];
  __syncthreads();
  #pragma unroll
  for (int i = 0; i < 32; i += 8)
    outb[(size_t)(c0 + ty + i) * R + (r0 + tx)] = __float2bfloat16(tile[tx][ty + i]);
}

// -------- 5-partial sum + transpose + bf16 cast: Ybt[c][r] = bf16(sum_s P_s[r][c])
__global__ __launch_bounds__(256) void tr_reduce5(
    const float* __restrict__ P0, const float* __restrict__ P14,
    bf16* __restrict__ out) {
  __shared__ float tile[32][33];
  int c0 = blockIdx.x * 32, r0 = blockIdx.y * 32;
  int tx = threadIdx.x & 31, ty = threadIdx.x >> 5;
  const size_t MN = (size_t)MROWS * DDIM;
  #pragma unroll
  for (int i = 0; i < 32; i += 8) {
    size_t idx = (size_t)(r0 + ty + i) * DDIM + (c0 + tx);
    tile[ty + i][tx] = P0[idx] + P14[idx] + P14[idx + MN] +
                       P14[idx + 2 * MN] + P14[idx + 3 * MN];
  }
  __syncthreads();
  #pragma unroll
  for (int i = 0; i < 32; i += 8)
    out[(size_t)(c0 + ty + i) * MROWS + (r0 + tx)] = __float2bfloat16(tile[tx][ty + i]);
}

// -------- y = sum of 4 f32 partials
__global__ __launch_bounds__(256) void reduce4(
    const float* __restrict__ P, float* __restrict__ y) {
  size_t i = ((size_t)blockIdx.x * 256 + threadIdx.x) * 4;
  const size_t MN = (size_t)LSEQ * DDIM;
  f32x4 a = *(const f32x4*)(P + i);
  f32x4 b = *(const f32x4*)(P + i + MN);
  f32x4 c = *(const f32x4*)(P + i + 2 * MN);
  f32x4 d = *(const f32x4*)(P + i + 3 * MN);
  *(f32x4*)(y + i) = a + b + c + d;
}

// -------- forward-DFT matrix, interleaved rows: W[2f][t]=cos, W[2f+1][t]=-sin
__global__ __launch_bounds__(256) void gen_w(bf16* __restrict__ W) {
  int r = blockIdx.y;
  int t0 = (blockIdx.x * 256 + threadIdx.x) * 8;
  bf16 o[8];
  if (r < FLIVE) {
    int f = r >> 1;
    bool odd = r & 1;
    #pragma unroll
    for (int i = 0; i < 8; ++i) {
      int m = (f * (t0 + i)) & (NFFT - 1);
      float rev = (float)m * (1.f / NFFT);
      float v = odd ? -fsin_rev(rev) : fcos_rev(rev);
      o[i] = __float2bfloat16(v);
    }
  } else {
    #pragma unroll
    for (int i = 0; i < 8; ++i) o[i] = __float2bfloat16(0.f);
  }
  *(s16x8*)(W + (size_t)r * LSEQ + t0) = *(const s16x8*)o;
}

// -------- inverse-DFT matrix: Cinv[l][2f]=wf/N*cos, Cinv[l][2f+1]=-wf/N*sin
__global__ __launch_bounds__(256) void gen_cinv(bf16* __restrict__ Cinv) {
  int l = blockIdx.y;
  int r0 = (blockIdx.x * 256 + threadIdx.x) * 8;
  if (r0 >= MROWS) return;
  bf16 o[8];
  #pragma unroll
  for (int p = 0; p < 4; ++p) {
    int rr = r0 + 2 * p;
    float v0 = 0.f, v1 = 0.f;
    if (rr < FLIVE) {
      int f = rr >> 1;
      int m = (f * l) & (NFFT - 1);
      float rev = (float)m * (1.f / NFFT);
      float wf = (f == 0 || f == NFFT / 2) ? 1.f : 2.f;
      float sc = wf * (1.f / NFFT);
      v0 = sc * fcos_rev(rev);
      v1 = -sc * fsin_rev(rev);
    }
    o[2 * p] = __float2bfloat16(v0);
    o[2 * p + 1] = __float2bfloat16(v1);
  }
  *(s16x8*)(Cinv + (size_t)l * MROWS + r0) = *(const s16x8*)o;
}

// -------- Pf[f][k] = sum_t phi[t][k] e^{-2pi i f t/N}, stored [f][k][re,im] f32
__global__ __launch_bounds__(256) void compute_pf(
    const float* __restrict__ phi, float* __restrict__ Pf) {
  int f = blockIdx.x;
  int tid = threadIdx.x;
  int lane = tid & 63, wave = tid >> 6;
  float pre[KFLT], pim[KFLT];
  #pragma unroll
  for (int k = 0; k < KFLT; ++k) { pre[k] = 0.f; pim[k] = 0.f; }
  for (int cch = 0; cch < LSEQ / 256; ++cch) {
    int t = cch * 256 + tid;
    int m = (f * t) & (NFFT - 1);
    float rev = (float)m * (1.f / NFFT);
    float s = fsin_rev(rev), c = fcos_rev(rev);
    const float4* pv = (const float4*)(phi + (size_t)t * KFLT);
    float4 v0 = pv[0], v1 = pv[1], v2 = pv[2], v3 = pv[3], v4 = pv[4], v5 = pv[5];
    float pr[KFLT] = {v0.x, v0.y, v0.z, v0.w, v1.x, v1.y, v1.z, v1.w,
                      v2.x, v2.y, v2.z, v2.w, v3.x, v3.y, v3.z, v3.w,
                      v4.x, v4.y, v4.z, v4.w, v5.x, v5.y, v5.z, v5.w};
    #pragma unroll
    for (int k = 0; k < KFLT; ++k) {
      pre[k] += pr[k] * c;
      pim[k] -= pr[k] * s;
    }
  }
  __shared__ float red[4][2 * KFLT];
  #pragma unroll
  for (int k = 0; k < KFLT; ++k) {
    float r = pre[k], i2 = pim[k];
    #pragma unroll
    for (int off = 32; off > 0; off >>= 1) {
      r += __shfl_down(r, off, 64);
      i2 += __shfl_down(i2, off, 64);
    }
    if (lane == 0) { red[wave][2 * k] = r; red[wave][2 * k + 1] = i2; }
  }
  __syncthreads();
  if (tid < 2 * KFLT)
    Pf[(size_t)f * (2 * KFLT) + tid] =
        red[0][tid] + red[1][tid] + red[2][tid] + red[3][tid];
}

// -------- Pw[j][f][re,im]: j<24 plus = Pf[f][k]; j>=24 minus = conj(Pf[4096-f][k])
__global__ __launch_bounds__(256) void build_pw(
    const float* __restrict__ Pf, float* __restrict__ Pw) {
  int idx = blockIdx.x * 256 + threadIdx.x;
  if (idx >= 48 * FPAD) return;
  int j = idx / FPAD, f = idx % FPAD;
  float re = 0.f, im = 0.f;
  if (f <= NFFT / 2) {
    if (j < KFLT) {
      re = Pf[(size_t)f * 48 + j * 2];
      im = Pf[(size_t)f * 48 + j * 2 + 1];
    } else {
      int k = j - KFLT, g = NFFT / 2 - f;
      re = Pf[(size_t)g * 48 + k * 2];
      im = -Pf[(size_t)g * 48 + k * 2 + 1];
    }
  }
  Pw[(size_t)idx * 2] = re;
  Pw[(size_t)idx * 2 + 1] = im;
}

// ======== direct GEMM (G1/G3): C = A[M,K] @ Bt[N,K]^T, BM=128 BN=256 BK=64,
// 8 waves 2x4 (wave 64x64), exact-cover grid, plain fused stores (NO atomics).
// STORE 0 (G1): grid 132 = 66 by x 2 bx, full K, bf16 store.
// STORE 1 (G3): grid 256 = (32 by x 2 bx) x 4 ksplit, f32 store to partial[ks].
template <int STORE>
__global__ __launch_bounds__(512, 2) void gemmD(
    const bf16* __restrict__ A, const bf16* __restrict__ Bt, int ldk,
    bf16* __restrict__ Obf, float* __restrict__ Of) {
  __shared__ bf16 sA[2 * 128 * 64];
  __shared__ bf16 sB[2 * 256 * 64];

  const int nwg = gridDim.x;
  const int lin = blockIdx.x;
  const int q8 = nwg >> 3, r8g = nwg & 7;
  const int xcd = lin & 7, pos = lin >> 3;
  const int wid = (xcd < r8g ? xcd * (q8 + 1) : r8g * (q8 + 1) + (xcd - r8g) * q8) + pos;

  int by, bx, kt0, nkt, ks;
  if constexpr (STORE == 0) { by = wid % 66; bx = wid / 66; kt0 = 0; nkt = 64; ks = 0; }
  else { int xy = wid & 63; ks = wid >> 6; by = xy >> 1; bx = xy & 1; kt0 = ks * 33; nkt = 33; }

  const int tid = threadIdx.x, lane = tid & 63, wave = tid >> 6;
  const int l15 = lane & 15, l4 = lane >> 4;
  const int wr = wave >> 2, wc = wave & 3;
  const int mtile = by * 128, ntile = bx * 256;
  const bf16* Ab = A + (size_t)mtile * ldk;
  const bf16* Bb = Bt + (size_t)ntile * ldk;

  f32x4 acc[4][4];
  #pragma unroll
  for (int m = 0; m < 4; ++m)
    #pragma unroll
    for (int n = 0; n < 4; ++n) acc[m][n] = f32x4{0.f, 0.f, 0.f, 0.f};

  stage_half(Ab + (size_t)kt0 * 64, ldk, sA, wave, lane);
  stage_half(Bb + (size_t)kt0 * 64, ldk, sB, wave, lane);
  stage_half(Bb + (size_t)128 * ldk + (size_t)kt0 * 64, ldk, sB + 128 * 64, wave, lane);
  asm volatile("s_waitcnt vmcnt(0)" ::: "memory");
  BAR();

  for (int t = 0; t < nkt; ++t) {
    const int par = t & 1, nb = par ^ 1;
    const bf16* bA = sA + par * (128 * 64);
    const bf16* bB = sB + par * (256 * 64);
    const bool more = (t + 1 < nkt);

    s16x8 afr[4][2], bfr[4][2];
    #pragma unroll
    for (int n = 0; n < 4; ++n)
      #pragma unroll
      for (int kk = 0; kk < 2; ++kk)
        bfr[n][kk] = ldfrag(bB, wc * 64 + n * 16 + l15, kk, l4);
    #pragma unroll
    for (int m = 0; m < 4; ++m)
      #pragma unroll
      for (int kk = 0; kk < 2; ++kk)
        afr[m][kk] = ldfrag(bA, wr * 64 + m * 16 + l15, kk, l4);

    if (more) {
      const size_t ko = (size_t)(kt0 + t + 1) * 64;
      stage_half(Ab + ko, ldk, sA + nb * (128 * 64), wave, lane);
      stage_half(Bb + ko, ldk, sB + nb * (256 * 64), wave, lane);
      stage_half(Bb + (size_t)128 * ldk + ko, ldk, sB + nb * (256 * 64) + 128 * 64,
                 wave, lane);
    }

    __builtin_amdgcn_s_setprio(1);
    #pragma unroll
    for (int m = 0; m < 4; ++m)
      #pragma unroll
      for (int n = 0; n < 4; ++n)
        #pragma unroll
        for (int kk = 0; kk < 2; ++kk)
          acc[m][n] = __builtin_amdgcn_mfma_f32_16x16x32_bf16(
              afr[m][kk], bfr[n][kk], acc[m][n], 0, 0, 0);
    __builtin_amdgcn_s_setprio(0);

    asm volatile("s_waitcnt vmcnt(0)" ::: "memory");
    BAR();
  }

  #pragma unroll
  for (int m = 0; m < 4; ++m)
    #pragma unroll
    for (int n = 0; n < 4; ++n)
      #pragma unroll
      for (int e = 0; e < 4; ++e) {
        int row = mtile + wr * 64 + m * 16 + l4 * 4 + e;
        int col = ntile + wc * 64 + n * 16 + l15;
        if constexpr (STORE == 0)
          Obf[(size_t)row * DDIM + col] = __float2bfloat16(acc[m][n][e]);
        else
          Of[(size_t)ks * LSEQ * DDIM + (size_t)row * DDIM + col] = acc[m][n][e];
      }
}

// ======== G2: Ysum = sum_j Pw[j] .* (Auf @ Mt_j^T) via PRE-WEIGHTED A.
// A'_j rows: [2f] = wre*U[2f] - wim*U[2f+1]; [2f+1] = wre*U[2f+1] + wim*U[2f]
// (row-pair mix = lane^8 shfl during reg-staging; ds_write with XOR swizzle).
// acc accumulates straight across all (j,kt) -> no yacc, no per-j flush.
// BM=256 BN=256, wave 128x64 (MA=8,NB=4). Persistent 256 blocks, 99 units each
// (unit = (xy, j, kt), 25344 total). Flush at xy boundary -> plain store to
// slot buffer wid%5 (writers of any xy-cell are <=5 consecutive wids).
__global__ __launch_bounds__(512, 2) void gemmW(
    const bf16* __restrict__ Auf, const bf16* __restrict__ Mt,
    const float* __restrict__ Pw, float* __restrict__ P0, float* __restrict__ P14) {
  __shared__ bf16 sA[2 * 256 * 64];
  __shared__ bf16 sB[2 * 256 * 64];

  const int lin = blockIdx.x;
  const int wid = (lin & 7) * 32 + (lin >> 3);      // contiguous ranges per XCD
  const int tid = threadIdx.x, lane = tid & 63, wave = tid >> 6;
  const int l15 = lane & 15, l4 = lane >> 4;
  const int wr = wave >> 2, wc = wave & 3;          // 2x4 waves
  const int r8 = lane >> 3, c8 = lane & 7;
  const float sgn = (r8 & 1) ? 1.f : -1.f;          // even row: re' = wre*re - wim*im

  const int g0 = wid * 99, g1 = g0 + 99;

  float* dst = (wid % 5 == 0) ? P0
             : P14 + (size_t)(wid % 5 - 1) * ((size_t)MROWS * DDIM);

  f32x4 acc[8][4];
  #pragma unroll
  for (int m = 0; m < 8; ++m)
    #pragma unroll
    for (int n = 0; n < 4; ++n) acc[m][n] = f32x4{0.f, 0.f, 0.f, 0.f};

  int4 adat[4];
  float2 wv[4];

  // decode unit g -> tiles
  auto decode = [&](int g, int& mt, int& nt, int& j, int& kt, int& xy) {
    xy = g / 384; int rem = g - xy * 384; j = rem >> 3; kt = rem & 7;
    mt = (xy % 33) * 256; nt = (xy / 33) * 256;
  };
  // issue A-row loads + weight loads for unit (mt, j, kt)
  auto issueA = [&](int mt, int j, int kt) {
    #pragma unroll
    for (int q = 0; q < 4; ++q) {
      int rl = (q >> 1) * 128 + (wave * 2 + (q & 1)) * 8 + r8;
      int rowg = mt + rl;
      adat[q] = *(const int4*)(Auf + (size_t)rowg * DDIM + kt * 64 + c8 * 8);
      wv[q] = *(const float2*)(Pw + ((size_t)j * FPAD + (rowg >> 1)) * 2);
    }
  };
  // complex-mix + swizzled ds_write into dstbase (256x64 tile)
  auto writeA = [&](bf16* dstbase) {
    #pragma unroll
    for (int q = 0; q < 4; ++q) {
      int rl = (q >> 1) * 128 + (wave * 2 + (q & 1)) * 8 + r8;
      int4 p;
      p.x = __shfl_xor(adat[q].x, 8, 64);
      p.y = __shfl_xor(adat[q].y, 8, 64);
      p.z = __shfl_xor(adat[q].z, 8, 64);
      p.w = __shfl_xor(adat[q].w, 8, 64);
      union { int4 i; unsigned short u[8]; } su, pu;
      su.i = adat[q]; pu.i = p;
      bf16 ob[8];
      #pragma unroll
      for (int e = 0; e < 8; ++e) {
        float fs = __uint_as_float((unsigned)su.u[e] << 16);
        float fp = __uint_as_float((unsigned)pu.u[e] << 16);
        ob[e] = __float2bfloat16(wv[q].x * fs + sgn * (wv[q].y * fp));
      }
      *(s16x8*)(dstbase + rl * 64 + ((c8 ^ r8) * 8)) = *(const s16x8*)ob;
    }
  };
  auto stageB = [&](int nt, int j, int kt, bf16* db) {
    const bf16* bb = Mt + (size_t)j * (DDIM * DDIM) + (size_t)nt * DDIM + kt * 64;
    stage_half(bb, DDIM, db, wave, lane);
    stage_half(bb + (size_t)128 * DDIM, DDIM, db + 128 * 64, wave, lane);
  };

  // ---- prologue: stage unit g0 into buffer 0
  int mt, nt, j, kt, xy;
  decode(g0, mt, nt, j, kt, xy);
  issueA(mt, j, kt);                                  // 8 vmem (data+w)
  stageB(nt, j, kt, sB);                              // 4 gld16
  asm volatile("s_waitcnt vmcnt(4)" ::: "memory");    // A data+w arrived
  writeA(sA);
  asm volatile("s_waitcnt vmcnt(0) lgkmcnt(0)" ::: "memory");
  BAR();

  int cxy = xy, cmt = mt, cnt_ = nt;

  for (int g = g0; g < g1; ++g) {
    const int par = (g - g0) & 1, nb = par ^ 1;
    const bf16* bA = sA + par * (256 * 64);
    const bf16* bB = sB + par * (256 * 64);
    const bool more = (g + 1 < g1);
    int nmt = 0, nnt = 0, nj = 0, nkt = 0, nxy = cxy;
    if (more) decode(g + 1, nmt, nnt, nj, nkt, nxy);

    // ---- phase 0: B frags + A frags m0..3; issue next-unit loads
    s16x8 bfr[4][2], afr[4][2];
    #pragma unroll
    for (int n = 0; n < 4; ++n)
      #pragma unroll
      for (int kk = 0; kk < 2; ++kk)
        bfr[n][kk] = ldfrag(bB, wc * 64 + n * 16 + l15, kk, l4);
    #pragma unroll
    for (int m = 0; m < 4; ++m)
      #pragma unroll
      for (int kk = 0; kk < 2; ++kk)
        afr[m][kk] = ldfrag(bA, wr * 128 + m * 16 + l15, kk, l4);
    if (more) {
      issueA(nmt, nj, nkt);                           // 8 vmem first
      stageB(nnt, nj, nkt, sB + nb * (256 * 64));     // then 4 gld16
    }
    __builtin_amdgcn_s_setprio(1);
    #pragma unroll
    for (int m = 0; m < 4; ++m)
      #pragma unroll
      for (int n = 0; n < 4; ++n)
        #pragma unroll
        for (int kk = 0; kk < 2; ++kk)
          acc[m][n] = __builtin_amdgcn_mfma_f32_16x16x32_bf16(
              afr[m][kk], bfr[n][kk], acc[m][n], 0, 0, 0);
    __builtin_amdgcn_s_setprio(0);

    // ---- phase 1: A frags m4..7; transform+write next A under MFMA shadow
    #pragma unroll
    for (int m = 0; m < 4; ++m)
      #pragma unroll
      for (int kk = 0; kk < 2; ++kk)
        afr[m][kk] = ldfrag(bA, wr * 128 + 64 + m * 16 + l15, kk, l4);
    if (more) {
      asm volatile("s_waitcnt vmcnt(4)" ::: "memory");  // A data+w done, B may fly
      writeA(sA + nb * (256 * 64));
    }
    __builtin_amdgcn_s_setprio(1);
    #pragma unroll
    for (int m = 0; m < 4; ++m)
      #pragma unroll
      for (int n = 0; n < 4; ++n)
        #pragma unroll
        for (int kk = 0; kk < 2; ++kk)
          acc[4 + m][n] = __builtin_amdgcn_mfma_f32_16x16x32_bf16(
              afr[m][kk], bfr[n][kk], acc[4 + m][n], 0, 0, 0);
    __builtin_amdgcn_s_setprio(0);

    asm volatile("s_waitcnt vmcnt(0) lgkmcnt(0)" ::: "memory");
    BAR();

    // ---- flush at xy boundary / range end (plain stores, slot buffer)
    if (!more || nxy != cxy) {
      #pragma unroll
      for (int m = 0; m < 8; ++m)
        #pragma unroll
        for (int n = 0; n < 4; ++n) {
          #pragma unroll
          for (int e = 0; e < 4; ++e) {
            int row = cmt + wr * 128 + (m & 3) * 16 + (m >> 2) * 64 + l4 * 4 + e;
            int col = cnt_ + wc * 64 + n * 16 + l15;
            dst[(size_t)row * DDIM + col] = acc[m][n][e];
          }
          acc[m][n] = f32x4{0.f, 0.f, 0.f, 0.f};
        }
    }
    cxy = nxy; cmt = nmt; cnt_ = nnt;
  }
}

// ---------------- workspace layout (bytes) ----------------
#define WS_W     0ULL                    // 8448*4096 bf16 = 69,206,016 (W / G2 slots P1..P4 / Cinv)
#define WS_AUF   69206016ULL             // 8448*512  bf16 =  8,650,752 (Auf / later G3 partials)
#define WS_UT    77856768ULL             // 512*4096  bf16 =  4,194,304
#define WS_MT    82051072ULL             // 48*512*512 bf16 = 25,165,824
#define WS_PF    107216896ULL            // 4097*48 f32    =    786,624
#define WS_PW    108003520ULL            // 48*4224*2 f32  =  1,622,016
#define WS_YSUM  109625536ULL            // 8448*512 f32   = 17,301,504 (G2 slot P0)
#define WS_YBT   126927040ULL            // 512*8448 bf16  =  8,650,752
#define WS_TOTAL 135577792ULL
// G3 partials: 4 x 4096*512 f32 = 33,554,432 at WS_AUF (Auf/uT/Mt dead by G3)

extern "C" void kernel_launch(void* const* d_in, const int* in_sizes, int n_in,
                              void* d_out, int out_size, void* d_ws, size_t ws_size,
                              hipStream_t stream) {
  const float* u   = (const float*)d_in[0];   // [4096, 512]
  const float* phi = (const float*)d_in[1];   // [4096, 24]
  const float* Mp  = (const float*)d_in[2];   // [24, 512, 512]
  const float* Mm  = (const float*)d_in[3];   // [24, 512, 512]
  float* y = (float*)d_out;                   // [4096, 512]

  if (ws_size < WS_TOTAL) return;             // loud failure: output stays zero

  char* ws = (char*)d_ws;
  bf16*  W    = (bf16*)(ws + WS_W);
  bf16*  Auf  = (bf16*)(ws + WS_AUF);
  bf16*  uT   = (bf16*)(ws + WS_UT);
  bf16*  Mt   = (bf16*)(ws + WS_MT);
  float* Pf   = (float*)(ws + WS_PF);
  float* Pw   = (float*)(ws + WS_PW);
  float* Ysum = (float*)(ws + WS_YSUM);
  bf16*  Ybt  = (bf16*)(ws + WS_YBT);
  float* P14  = (float*)(ws + WS_W);          // G2 slots 1..4 (reuse W region)
  float* G3P  = (float*)(ws + WS_AUF);        // G3 partials (reuse Auf/uT/Mt)

  // prologue: transposed bf16 operands + spectral weight tables
  transpose_cast<<<dim3(16, 128, 1), 256, 0, stream>>>(u, uT, LSEQ, DDIM);
  transpose_cast<<<dim3(16, 16, 24), 256, 0, stream>>>(Mp, Mt, DDIM, DDIM);
  transpose_cast<<<dim3(16, 16, 24), 256, 0, stream>>>(Mm, Mt + (size_t)24 * DDIM * DDIM,
                                                       DDIM, DDIM);
  gen_w<<<dim3(2, MROWS), 256, 0, stream>>>(W);
  compute_pf<<<dim3(4097), 256, 0, stream>>>(phi, Pf);
  build_pw<<<dim3((48 * FPAD + 255) / 256), 256, 0, stream>>>(Pf, Pw);

  // G1: Auf = bf16(Wdft @ u), exact-cover 132 blocks, fused bf16 store
  gemmD<0><<<132, 512, 0, stream>>>(W, uT, LSEQ, Auf, nullptr);

  // G2: pre-weighted persistent GEMM into 5 slot buffers (zeroed first; W now dead)
  hipMemsetAsync(Ysum, 0, (size_t)MROWS * DDIM * sizeof(float), stream);
  hipMemsetAsync(P14, 0, 4ULL * MROWS * DDIM * sizeof(float), stream);
  gemmW<<<256, 512, 0, stream>>>(Auf, Mt, Pw, Ysum, P14);

  // Ybt = bf16((sum of 5 slots)^T); then Cinv overwrites W region
  tr_reduce5<<<dim3(16, 264), 256, 0, stream>>>(Ysum, P14, Ybt);
  gen_cinv<<<dim3(5, LSEQ), 256, 0, stream>>>(W);

  // G3: 4 ksplit partials (exact cover, no memset), then reduce into y
  gemmD<1><<<256, 512, 0, stream>>>(W, Ybt, MROWS, nullptr, G3P);
  reduce4<<<dim3(LSEQ * DDIM / (256 * 4)), 256, 0, stream>>>(G3P, y);
}